// Round 1
// baseline (384.036 us; speedup 1.0000x reference)
//
#include <hip/hip_runtime.h>
#include <hip/hip_bf16.h>
#include <math.h>

#define T_DIM 2048
#define D_DIM 2048
#define H_DIM 16
#define C_DIM 128

typedef __bf16 bf16;
typedef __attribute__((ext_vector_type(8))) __bf16 bf16x8;
typedef __attribute__((ext_vector_type(4))) __bf16 bf16x4;
typedef __attribute__((ext_vector_type(2))) __bf16 bf16x2;
typedef __attribute__((ext_vector_type(4))) float f32x4;

__device__ __forceinline__ void gload_lds16(const void* g, void* l) {
  __builtin_amdgcn_global_load_lds((__attribute__((address_space(1))) void*)g,
                                   (__attribute__((address_space(3))) void*)l,
                                   16, 0, 0);
}

// ---------------- fp32 -> bf16 conversion (vectorized) ----------------
__global__ __launch_bounds__(256) void cvt_f32_to_bf16(
    const float* __restrict__ src, bf16* __restrict__ dst, int n4)
{
  int i = blockIdx.x * blockDim.x + threadIdx.x;
  int stride = gridDim.x * blockDim.x;
  for (; i < n4; i += stride) {
    float4 v = reinterpret_cast<const float4*>(src)[i];
    bf16x4 o;
    o[0] = (bf16)v.x; o[1] = (bf16)v.y; o[2] = (bf16)v.z; o[3] = (bf16)v.w;
    reinterpret_cast<bf16x4*>(dst)[i] = o;
  }
}

// ---------------- GEMM: C(MxN) = A(MxK) @ B(NxK)^T + bias, fp32 out ----------------
// m97 structure: 128x128 tile, BK=32, 4 waves (2x2 of 64x64), global_load_lds(16B).
__global__ __launch_bounds__(256) void gemm_bt_bias(
    const bf16* __restrict__ A, const bf16* __restrict__ B,
    const float* __restrict__ bias, float* __restrict__ C,
    int M, int N, int K)
{
  __shared__ __align__(16) bf16 As[128 * 32];
  __shared__ __align__(16) bf16 Bs[128 * 32];
  const int tid = threadIdx.x;
  const int lane = tid & 63;
  const int w = tid >> 6;
  const int wm = (w >> 1) * 64, wn = (w & 1) * 64;
  const int g = lane >> 4;
  const int r16 = lane & 15;
  const int bm = blockIdx.y, bn = blockIdx.x;

  f32x4 acc[4][4] = {};

  const size_t Abase = (size_t)(bm * 128) * K;
  const size_t Bbase = (size_t)(bn * 128) * K;

  for (int k0 = 0; k0 < K; k0 += 32) {
#pragma unroll
    for (int c = 0; c < 2; ++c) {
      int e = c * 256 + tid;
      int row = e >> 2, col = (e & 3) * 8;
      gload_lds16(A + Abase + (size_t)row * K + k0 + col, (char*)As + (size_t)e * 16);
      gload_lds16(B + Bbase + (size_t)row * K + k0 + col, (char*)Bs + (size_t)e * 16);
    }
    __syncthreads();
    bf16x8 a[4], b[4];
#pragma unroll
    for (int m = 0; m < 4; ++m)
      a[m] = *reinterpret_cast<const bf16x8*>(&As[(wm + m * 16 + r16) * 32 + g * 8]);
#pragma unroll
    for (int n = 0; n < 4; ++n)
      b[n] = *reinterpret_cast<const bf16x8*>(&Bs[(wn + n * 16 + r16) * 32 + g * 8]);
#pragma unroll
    for (int m = 0; m < 4; ++m)
#pragma unroll
      for (int n = 0; n < 4; ++n)
        acc[m][n] = __builtin_amdgcn_mfma_f32_16x16x32_bf16(a[m], b[n], acc[m][n], 0, 0, 0);
    __syncthreads();
  }

#pragma unroll
  for (int m = 0; m < 4; ++m) {
    int row0 = bm * 128 + wm + m * 16 + g * 4;
#pragma unroll
    for (int n = 0; n < 4; ++n) {
      int col = bn * 128 + wn + n * 16 + r16;
      float bv = bias[col];
#pragma unroll
      for (int rr = 0; rr < 4; ++rr)
        C[(size_t)(row0 + rr) * N + col] = acc[m][n][rr] + bv;
    }
  }
}

// ---------------- LayerNorm + RoPE + pack q/k to bf16 [h][t][c] ----------------
__global__ __launch_bounds__(256) void ln_rope_kernel(
    const float* __restrict__ qkv, const float* __restrict__ qw,
    const float* __restrict__ kw, bf16* __restrict__ qo, bf16* __restrict__ ko)
{
  const int tid = threadIdx.x;
  const int lane = tid & 63;
  const int wid = blockIdx.x * 4 + (tid >> 6);
  const int h = wid >> 11;          // / T
  const int t = wid & (T_DIM - 1);
  const int c0 = lane * 2;

  // inv_freq = 10000^(-c0/128); freqs = t * inv_freq
  float inv_freq = exp2f(-13.287712379549449f * (float)c0 * (1.0f / 128.0f));
  float fr = (float)t * inv_freq;
  float sn = sinf(fr), cs = cosf(fr);
  const float scaleq = 0.08838834764831845f; // 1/sqrt(128)

#pragma unroll
  for (int which = 0; which < 2; ++which) {
    const float* base = qkv + (size_t)t * (3 * D_DIM) + which * D_DIM + h * C_DIM;
    float2 v = *reinterpret_cast<const float2*>(base + c0);
    float s = v.x + v.y;
#pragma unroll
    for (int m = 32; m; m >>= 1) s += __shfl_xor(s, m);
    float mu = s * (1.0f / 128.0f);
    float d0 = v.x - mu, d1 = v.y - mu;
    float ss = d0 * d0 + d1 * d1;
#pragma unroll
    for (int m = 32; m; m >>= 1) ss += __shfl_xor(ss, m);
    float rstd = rsqrtf(ss * (1.0f / 128.0f) + 1e-6f);
    const float* wgt = which ? kw : qw;
    float x0 = d0 * rstd * wgt[c0], x1 = d1 * rstd * wgt[c0 + 1];
    float o0 = x0 * cs - x1 * sn;
    float o1 = x1 * cs + x0 * sn;
    if (!which) { o0 *= scaleq; o1 *= scaleq; }
    bf16* out = (which ? ko : qo) + ((size_t)h * T_DIM + t) * C_DIM + c0;
    bf16x2 ob; ob[0] = (bf16)o0; ob[1] = (bf16)o1;
    *reinterpret_cast<bf16x2*>(out) = ob;
  }
}

// ---------------- V transpose: qkv v-part (t,c) -> vt bf16 [h][c][t] ----------------
__global__ __launch_bounds__(256) void v_transpose_kernel(
    const float* __restrict__ qkv, bf16* __restrict__ vt)
{
  __shared__ bf16 tile[32][33];
  const int h = blockIdx.z;
  const int t0 = blockIdx.x * 32, c0 = blockIdx.y * 32;
  const int tx = threadIdx.x, ty = threadIdx.y;
#pragma unroll
  for (int i = 0; i < 4; ++i) {
    int t = t0 + ty + i * 8;
    tile[ty + i * 8][tx] =
        (bf16)qkv[(size_t)t * (3 * D_DIM) + 2 * D_DIM + h * C_DIM + c0 + tx];
  }
  __syncthreads();
#pragma unroll
  for (int i = 0; i < 4; ++i) {
    int c = c0 + ty + i * 8;
    vt[((size_t)h * C_DIM + c) * T_DIM + t0 + tx] = tile[tx][ty + i * 8];
  }
}

// ---------------- Flash attention (causal), 4 waves x 16 q-rows, KVB=64 ----------------
__global__ __launch_bounds__(256) void attn_kernel(
    const bf16* __restrict__ Q, const bf16* __restrict__ K,
    const bf16* __restrict__ VT, bf16* __restrict__ AO)
{
  __shared__ __align__(16) bf16 p_lds[4][16][72]; // 64 used + pad to 72 (16B-aligned rows)
  const int tid = threadIdx.x;
  const int lane = tid & 63;
  const int w = tid >> 6;
  const int g = lane >> 4, r16 = lane & 15;
  const int h = blockIdx.y;
  const int q0 = blockIdx.x * 64;
  const int qr0 = q0 + w * 16;

  const bf16* Qh = Q + (size_t)h * T_DIM * C_DIM;
  const bf16* Kh = K + (size_t)h * T_DIM * C_DIM;
  const bf16* Vh = VT + (size_t)h * C_DIM * T_DIM;

  bf16x8 qf[4];
#pragma unroll
  for (int kk = 0; kk < 4; ++kk)
    qf[kk] = *reinterpret_cast<const bf16x8*>(
        &Qh[(size_t)(qr0 + r16) * C_DIM + kk * 32 + g * 8]);

  float mrow[4] = {-INFINITY, -INFINITY, -INFINITY, -INFINITY};
  float lrow[4] = {0.f, 0.f, 0.f, 0.f};
  f32x4 o[8] = {};

  const int nkb = blockIdx.x + 1;
  for (int kb = 0; kb < nkb; ++kb) {
    f32x4 sacc[4] = {};
#pragma unroll
    for (int n = 0; n < 4; ++n) {
#pragma unroll
      for (int kk = 0; kk < 4; ++kk) {
        bf16x8 kf = *reinterpret_cast<const bf16x8*>(
            &Kh[(size_t)(kb * 64 + n * 16 + r16) * C_DIM + kk * 32 + g * 8]);
        sacc[n] = __builtin_amdgcn_mfma_f32_16x16x32_bf16(qf[kk], kf, sacc[n], 0, 0, 0);
      }
    }
    // causal mask (only needed on partial/diagonal blocks)
    if (!(kb * 64 + 63 <= qr0)) {
#pragma unroll
      for (int n = 0; n < 4; ++n) {
        int key = kb * 64 + n * 16 + r16;
#pragma unroll
        for (int rr = 0; rr < 4; ++rr) {
          int qrow = qr0 + g * 4 + rr;
          if (key > qrow) sacc[n][rr] = -3.0e38f;
        }
      }
    }
    // online softmax (per q-row: reduce across 16-lane groups)
    float alpha[4];
#pragma unroll
    for (int rr = 0; rr < 4; ++rr) {
      float mx = fmaxf(fmaxf(sacc[0][rr], sacc[1][rr]),
                       fmaxf(sacc[2][rr], sacc[3][rr]));
      mx = fmaxf(mx, __shfl_xor(mx, 1));
      mx = fmaxf(mx, __shfl_xor(mx, 2));
      mx = fmaxf(mx, __shfl_xor(mx, 4));
      mx = fmaxf(mx, __shfl_xor(mx, 8));
      float mnew = fmaxf(mrow[rr], mx);
      alpha[rr] = __expf(mrow[rr] - mnew);
      mrow[rr] = mnew;
      float ps = 0.f;
#pragma unroll
      for (int n = 0; n < 4; ++n) {
        float p = __expf(sacc[n][rr] - mnew);
        sacc[n][rr] = p;
        ps += p;
      }
      ps += __shfl_xor(ps, 1); ps += __shfl_xor(ps, 2);
      ps += __shfl_xor(ps, 4); ps += __shfl_xor(ps, 8);
      lrow[rr] = lrow[rr] * alpha[rr] + ps;
    }
#pragma unroll
    for (int nc = 0; nc < 8; ++nc)
#pragma unroll
      for (int rr = 0; rr < 4; ++rr)
        o[nc][rr] *= alpha[rr];
    // P -> LDS bounce (per-wave slice; layout change to A-fragment order)
#pragma unroll
    for (int n = 0; n < 4; ++n)
#pragma unroll
      for (int rr = 0; rr < 4; ++rr)
        p_lds[w][g * 4 + rr][n * 16 + r16] = (bf16)sacc[n][rr];
    asm volatile("s_waitcnt lgkmcnt(0)" ::: "memory");
    // PV
#pragma unroll
    for (int kk2 = 0; kk2 < 2; ++kk2) {
      bf16x8 pf = *reinterpret_cast<const bf16x8*>(&p_lds[w][r16][kk2 * 32 + g * 8]);
#pragma unroll
      for (int nc = 0; nc < 8; ++nc) {
        bf16x8 vf = *reinterpret_cast<const bf16x8*>(
            &Vh[(size_t)(nc * 16 + r16) * T_DIM + kb * 64 + kk2 * 32 + g * 8]);
        o[nc] = __builtin_amdgcn_mfma_f32_16x16x32_bf16(pf, vf, o[nc], 0, 0, 0);
      }
    }
  }
  // epilogue: normalize, write bf16 [t][h*C+c]
#pragma unroll
  for (int rr = 0; rr < 4; ++rr) {
    float inv = 1.0f / lrow[rr];
    int trow = qr0 + g * 4 + rr;
#pragma unroll
    for (int nc = 0; nc < 8; ++nc)
      AO[(size_t)trow * D_DIM + h * C_DIM + nc * 16 + r16] = (bf16)(o[nc][rr] * inv);
  }
}

// ---------------- launch ----------------
extern "C" void kernel_launch(void* const* d_in, const int* in_sizes, int n_in,
                              void* d_out, int out_size, void* d_ws, size_t ws_size,
                              hipStream_t stream)
{
  const float* x      = (const float*)d_in[0];
  const float* W_attn = (const float*)d_in[1];
  const float* b_attn = (const float*)d_in[2];
  const float* W_proj = (const float*)d_in[3];
  const float* b_proj = (const float*)d_in[4];
  const float* q_ln_w = (const float*)d_in[5];
  const float* k_ln_w = (const float*)d_in[6];

  char* ws = (char*)d_ws;
  bf16*  x_bf  = (bf16*)(ws + 0);           //  8 MB
  bf16*  wa_bf = (bf16*)(ws + 8388608);     // 24 MB
  bf16*  wp_bf = (bf16*)(ws + 33554432);    //  8 MB
  float* qkv   = (float*)(ws + 41943040);   // 48 MB
  bf16*  q_bf  = (bf16*)(ws + 92274688);    //  8 MB
  bf16*  k_bf  = (bf16*)(ws + 100663296);   //  8 MB
  bf16*  vt    = (bf16*)(ws + 109051904);   //  8 MB
  bf16*  ao    = (bf16*)(ws + 117440512);   //  8 MB (total 120 MB)

  cvt_f32_to_bf16<<<2048, 256, 0, stream>>>(x,      x_bf,  T_DIM * D_DIM / 4);
  cvt_f32_to_bf16<<<2048, 256, 0, stream>>>(W_attn, wa_bf, 3 * D_DIM * D_DIM / 4);
  cvt_f32_to_bf16<<<2048, 256, 0, stream>>>(W_proj, wp_bf, D_DIM * D_DIM / 4);

  gemm_bt_bias<<<dim3(3 * D_DIM / 128, T_DIM / 128), 256, 0, stream>>>(
      x_bf, wa_bf, b_attn, qkv, T_DIM, 3 * D_DIM, D_DIM);

  ln_rope_kernel<<<(H_DIM * T_DIM) / 4, 256, 0, stream>>>(qkv, q_ln_w, k_ln_w, q_bf, k_bf);
  v_transpose_kernel<<<dim3(T_DIM / 32, C_DIM / 32, H_DIM), dim3(32, 8), 0, stream>>>(qkv, vt);

  attn_kernel<<<dim3(T_DIM / 64, H_DIM), 256, 0, stream>>>(q_bf, k_bf, vt, ao);

  gemm_bt_bias<<<dim3(D_DIM / 128, T_DIM / 128), 256, 0, stream>>>(
      ao, wp_bf, b_proj, (float*)d_out, T_DIM, D_DIM, D_DIM);
}

// Round 2
// 241.141 us; speedup vs baseline: 1.5926x; 1.5926x over previous
//
#include <hip/hip_runtime.h>
#include <hip/hip_bf16.h>
#include <math.h>

#define T_DIM 2048
#define D_DIM 2048
#define H_DIM 16
#define C_DIM 128

typedef __bf16 bf16;
typedef __attribute__((ext_vector_type(8))) __bf16 bf16x8;
typedef __attribute__((ext_vector_type(4))) __bf16 bf16x4;
typedef __attribute__((ext_vector_type(2))) __bf16 bf16x2;
typedef __attribute__((ext_vector_type(4))) float f32x4;

__device__ __forceinline__ void gload_lds16(const void* g, void* l) {
  __builtin_amdgcn_global_load_lds((__attribute__((address_space(1))) void*)g,
                                   (__attribute__((address_space(3))) void*)l,
                                   16, 0, 0);
}

// ---------------- fp32 -> bf16 conversion (vectorized) ----------------
__global__ __launch_bounds__(256) void cvt_f32_to_bf16(
    const float* __restrict__ src, bf16* __restrict__ dst, int n4)
{
  int i = blockIdx.x * blockDim.x + threadIdx.x;
  int stride = gridDim.x * blockDim.x;
  for (; i < n4; i += stride) {
    float4 v = reinterpret_cast<const float4*>(src)[i];
    bf16x4 o;
    o[0] = (bf16)v.x; o[1] = (bf16)v.y; o[2] = (bf16)v.z; o[3] = (bf16)v.w;
    reinterpret_cast<bf16x4*>(dst)[i] = o;
  }
}

// ---------------- GEMM: C(MxN) = A(MxK) @ B(NxK)^T + bias, fp32 out ----------------
__global__ __launch_bounds__(256) void gemm_bt_bias(
    const bf16* __restrict__ A, const bf16* __restrict__ B,
    const float* __restrict__ bias, float* __restrict__ C,
    int M, int N, int K)
{
  __shared__ __align__(16) bf16 As[128 * 32];
  __shared__ __align__(16) bf16 Bs[128 * 32];
  const int tid = threadIdx.x;
  const int lane = tid & 63;
  const int w = tid >> 6;
  const int wm = (w >> 1) * 64, wn = (w & 1) * 64;
  const int g = lane >> 4;
  const int r16 = lane & 15;
  const int bm = blockIdx.y, bn = blockIdx.x;

  f32x4 acc[4][4] = {};

  const size_t Abase = (size_t)(bm * 128) * K;
  const size_t Bbase = (size_t)(bn * 128) * K;

  for (int k0 = 0; k0 < K; k0 += 32) {
#pragma unroll
    for (int c = 0; c < 2; ++c) {
      int e = c * 256 + tid;
      int row = e >> 2, col = (e & 3) * 8;
      gload_lds16(A + Abase + (size_t)row * K + k0 + col, (char*)As + (size_t)e * 16);
      gload_lds16(B + Bbase + (size_t)row * K + k0 + col, (char*)Bs + (size_t)e * 16);
    }
    __syncthreads();
    bf16x8 a[4], b[4];
#pragma unroll
    for (int m = 0; m < 4; ++m)
      a[m] = *reinterpret_cast<const bf16x8*>(&As[(wm + m * 16 + r16) * 32 + g * 8]);
#pragma unroll
    for (int n = 0; n < 4; ++n)
      b[n] = *reinterpret_cast<const bf16x8*>(&Bs[(wn + n * 16 + r16) * 32 + g * 8]);
#pragma unroll
    for (int m = 0; m < 4; ++m)
#pragma unroll
      for (int n = 0; n < 4; ++n)
        acc[m][n] = __builtin_amdgcn_mfma_f32_16x16x32_bf16(a[m], b[n], acc[m][n], 0, 0, 0);
    __syncthreads();
  }

#pragma unroll
  for (int m = 0; m < 4; ++m) {
    int row0 = bm * 128 + wm + m * 16 + g * 4;
#pragma unroll
    for (int n = 0; n < 4; ++n) {
      int col = bn * 128 + wn + n * 16 + r16;
      float bv = bias[col];
#pragma unroll
      for (int rr = 0; rr < 4; ++rr)
        C[(size_t)(row0 + rr) * N + col] = acc[m][n][rr] + bv;
    }
  }
}

// ---------------- LayerNorm + RoPE + pack q/k to bf16 [h][t][c] ----------------
__global__ __launch_bounds__(256) void ln_rope_kernel(
    const float* __restrict__ qkv, const float* __restrict__ qw,
    const float* __restrict__ kw, bf16* __restrict__ qo, bf16* __restrict__ ko)
{
  const int tid = threadIdx.x;
  const int lane = tid & 63;
  const int wid = blockIdx.x * 4 + (tid >> 6);
  const int h = wid >> 11;          // / T
  const int t = wid & (T_DIM - 1);
  const int c0 = lane * 2;

  float inv_freq = exp2f(-13.287712379549449f * (float)c0 * (1.0f / 128.0f));
  float fr = (float)t * inv_freq;
  float sn = sinf(fr), cs = cosf(fr);
  const float scaleq = 0.08838834764831845f; // 1/sqrt(128)

#pragma unroll
  for (int which = 0; which < 2; ++which) {
    const float* base = qkv + (size_t)t * (3 * D_DIM) + which * D_DIM + h * C_DIM;
    float2 v = *reinterpret_cast<const float2*>(base + c0);
    float s = v.x + v.y;
#pragma unroll
    for (int m = 32; m; m >>= 1) s += __shfl_xor(s, m);
    float mu = s * (1.0f / 128.0f);
    float d0 = v.x - mu, d1 = v.y - mu;
    float ss = d0 * d0 + d1 * d1;
#pragma unroll
    for (int m = 32; m; m >>= 1) ss += __shfl_xor(ss, m);
    float rstd = rsqrtf(ss * (1.0f / 128.0f) + 1e-6f);
    const float* wgt = which ? kw : qw;
    float x0 = d0 * rstd * wgt[c0], x1 = d1 * rstd * wgt[c0 + 1];
    float o0 = x0 * cs - x1 * sn;
    float o1 = x1 * cs + x0 * sn;
    if (!which) { o0 *= scaleq; o1 *= scaleq; }
    bf16* out = (which ? ko : qo) + ((size_t)h * T_DIM + t) * C_DIM + c0;
    bf16x2 ob; ob[0] = (bf16)o0; ob[1] = (bf16)o1;
    *reinterpret_cast<bf16x2*>(out) = ob;
  }
}

// ---------------- V transpose: qkv v-part (t,c) -> vt bf16 [h][c][t] ----------------
__global__ __launch_bounds__(256) void v_transpose_kernel(
    const float* __restrict__ qkv, bf16* __restrict__ vt)
{
  __shared__ bf16 tile[32][33];
  const int h = blockIdx.z;
  const int t0 = blockIdx.x * 32, c0 = blockIdx.y * 32;
  const int tx = threadIdx.x, ty = threadIdx.y;
#pragma unroll
  for (int i = 0; i < 4; ++i) {
    int t = t0 + ty + i * 8;
    tile[ty + i * 8][tx] =
        (bf16)qkv[(size_t)t * (3 * D_DIM) + 2 * D_DIM + h * C_DIM + c0 + tx];
  }
  __syncthreads();
#pragma unroll
  for (int i = 0; i < 4; ++i) {
    int c = c0 + ty + i * 8;
    vt[((size_t)h * C_DIM + c) * T_DIM + t0 + tx] = tile[tx][ty + i * 8];
  }
}

// ---------------- Flash attention (causal), 4 waves x 16 q-rows, KVB=64 ----------------
// K/V staged in LDS (double-buffered, global_load_lds width 16) with XOR chunk
// swizzle applied on the GLOBAL source (linear LDS dest) + matching XOR on reads.
__global__ __launch_bounds__(256) void attn_kernel(
    const bf16* __restrict__ Q, const bf16* __restrict__ K,
    const bf16* __restrict__ VT, bf16* __restrict__ AO)
{
  __shared__ __align__(16) bf16 Ks[2][64 * 128];   // 32 KB
  __shared__ __align__(16) bf16 Vs[2][128 * 64];   // 32 KB
  __shared__ __align__(16) bf16 p_lds[4][16 * 64]; //  8 KB
  const int tid = threadIdx.x;
  const int lane = tid & 63;
  const int w = tid >> 6;
  const int g = lane >> 4, r16 = lane & 15;
  const int h = blockIdx.y;
  const int qb = gridDim.x - 1 - blockIdx.x;  // long blocks first
  const int q0 = qb * 64;
  const int qr0 = q0 + w * 16;

  const bf16* Qh = Q + (size_t)h * T_DIM * C_DIM;
  const bf16* Kh = K + (size_t)h * T_DIM * C_DIM;
  const bf16* Vh = VT + (size_t)h * C_DIM * T_DIM;

  bf16x8 qf[4];
#pragma unroll
  for (int kk = 0; kk < 4; ++kk)
    qf[kk] = *reinterpret_cast<const bf16x8*>(
        &Qh[(size_t)(qr0 + r16) * C_DIM + kk * 32 + g * 8]);

  float mrow[4] = {-INFINITY, -INFINITY, -INFINITY, -INFINITY};
  float lrow[4] = {0.f, 0.f, 0.f, 0.f};
  f32x4 o[8] = {};

  const int nkb = qb + 1;

  // stage K(64x128) + V(128x64) tile kb into buf; 8 x 16B per thread.
  auto stage = [&](int buf, int kb) {
    const bf16* Kt = Kh + (size_t)(kb * 64) * C_DIM;
    const bf16* Vt = Vh + kb * 64;
#pragma unroll
    for (int i = 0; i < 4; ++i) {
      int e = i * 256 + tid;
      int r = e >> 4, p = e & 15, j = p ^ (r & 7);
      gload_lds16(Kt + r * C_DIM + j * 8, (char*)&Ks[buf][0] + (size_t)e * 16);
    }
#pragma unroll
    for (int i = 0; i < 4; ++i) {
      int e = i * 256 + tid;
      int r = e >> 3, p = e & 7, j = p ^ (r & 7);
      gload_lds16(Vt + (size_t)r * T_DIM + j * 8, (char*)&Vs[buf][0] + (size_t)e * 16);
    }
  };

  stage(0, 0);
  __syncthreads();  // drains vmcnt: tile 0 ready
  int buf = 0;

  for (int kb = 0; kb < nkb; ++kb) {
    if (kb + 1 < nkb) stage(buf ^ 1, kb + 1);  // issue next-tile loads; latency hides under compute

    // ---- QK^T from LDS (swizzled reads, conflict-free) ----
    f32x4 sacc[4] = {};
#pragma unroll
    for (int n = 0; n < 4; ++n) {
      int kr = n * 16 + r16;
      const bf16* kbase = &Ks[buf][kr << 7];
#pragma unroll
      for (int kk = 0; kk < 4; ++kk) {
        bf16x8 kf = *reinterpret_cast<const bf16x8*>(
            kbase + (((kk * 4 + g) ^ (kr & 7)) << 3));
        sacc[n] = __builtin_amdgcn_mfma_f32_16x16x32_bf16(qf[kk], kf, sacc[n], 0, 0, 0);
      }
    }
    // causal mask (only on diagonal-crossing blocks)
    if (!(kb * 64 + 63 <= qr0)) {
#pragma unroll
      for (int n = 0; n < 4; ++n) {
        int key = kb * 64 + n * 16 + r16;
#pragma unroll
        for (int rr = 0; rr < 4; ++rr) {
          int qrow = qr0 + g * 4 + rr;
          if (key > qrow) sacc[n][rr] = -3.0e38f;
        }
      }
    }
    // ---- online softmax (per q-row; reduce across 16-lane groups) ----
    float alpha[4];
#pragma unroll
    for (int rr = 0; rr < 4; ++rr) {
      float mx = fmaxf(fmaxf(sacc[0][rr], sacc[1][rr]),
                       fmaxf(sacc[2][rr], sacc[3][rr]));
      mx = fmaxf(mx, __shfl_xor(mx, 1));
      mx = fmaxf(mx, __shfl_xor(mx, 2));
      mx = fmaxf(mx, __shfl_xor(mx, 4));
      mx = fmaxf(mx, __shfl_xor(mx, 8));
      float mnew = fmaxf(mrow[rr], mx);
      alpha[rr] = __expf(mrow[rr] - mnew);
      mrow[rr] = mnew;
      float ps = 0.f;
#pragma unroll
      for (int n = 0; n < 4; ++n) {
        float p = __expf(sacc[n][rr] - mnew);
        sacc[n][rr] = p;
        ps += p;
      }
      ps += __shfl_xor(ps, 1); ps += __shfl_xor(ps, 2);
      ps += __shfl_xor(ps, 4); ps += __shfl_xor(ps, 8);
      lrow[rr] = lrow[rr] * alpha[rr] + ps;
    }
#pragma unroll
    for (int nc = 0; nc < 8; ++nc)
#pragma unroll
      for (int rr = 0; rr < 4; ++rr)
        o[nc][rr] *= alpha[rr];
    // ---- P -> LDS bounce (XOR-swizzled scalar writes) ----
#pragma unroll
    for (int n = 0; n < 4; ++n)
#pragma unroll
      for (int rr = 0; rr < 4; ++rr) {
        int row = g * 4 + rr, col = n * 16 + r16;
        p_lds[w][(row << 6) + ((((col >> 3) ^ (row & 7)) << 3)) + (col & 7)] =
            (bf16)sacc[n][rr];
      }
    asm volatile("s_waitcnt lgkmcnt(0)" ::: "memory");
    // ---- PV from LDS (swizzled reads, conflict-free) ----
#pragma unroll
    for (int kk2 = 0; kk2 < 2; ++kk2) {
      bf16x8 pf = *reinterpret_cast<const bf16x8*>(
          &p_lds[w][(r16 << 6) + (((kk2 * 4 + g) ^ (r16 & 7)) << 3)]);
#pragma unroll
      for (int nc = 0; nc < 8; ++nc) {
        int vr = nc * 16 + r16;
        bf16x8 vf = *reinterpret_cast<const bf16x8*>(
            &Vs[buf][(vr << 6) + (((kk2 * 4 + g) ^ (vr & 7)) << 3)]);
        o[nc] = __builtin_amdgcn_mfma_f32_16x16x32_bf16(pf, vf, o[nc], 0, 0, 0);
      }
    }
    __syncthreads();  // drains vmcnt (next tile ready) + all waves done reading buf
    buf ^= 1;
  }
  // epilogue: normalize, write bf16 [t][h*C+c]
#pragma unroll
  for (int rr = 0; rr < 4; ++rr) {
    float inv = 1.0f / lrow[rr];
    int trow = qr0 + g * 4 + rr;
#pragma unroll
    for (int nc = 0; nc < 8; ++nc)
      AO[(size_t)trow * D_DIM + h * C_DIM + nc * 16 + r16] = (bf16)(o[nc][rr] * inv);
  }
}

// ---------------- launch ----------------
extern "C" void kernel_launch(void* const* d_in, const int* in_sizes, int n_in,
                              void* d_out, int out_size, void* d_ws, size_t ws_size,
                              hipStream_t stream)
{
  const float* x      = (const float*)d_in[0];
  const float* W_attn = (const float*)d_in[1];
  const float* b_attn = (const float*)d_in[2];
  const float* W_proj = (const float*)d_in[3];
  const float* b_proj = (const float*)d_in[4];
  const float* q_ln_w = (const float*)d_in[5];
  const float* k_ln_w = (const float*)d_in[6];

  char* ws = (char*)d_ws;
  bf16*  x_bf  = (bf16*)(ws + 0);           //  8 MB
  bf16*  wa_bf = (bf16*)(ws + 8388608);     // 24 MB
  bf16*  wp_bf = (bf16*)(ws + 33554432);    //  8 MB
  float* qkv   = (float*)(ws + 41943040);   // 48 MB
  bf16*  q_bf  = (bf16*)(ws + 92274688);    //  8 MB
  bf16*  k_bf  = (bf16*)(ws + 100663296);   //  8 MB
  bf16*  vt    = (bf16*)(ws + 109051904);   //  8 MB
  bf16*  ao    = (bf16*)(ws + 117440512);   //  8 MB (total 120 MB)

  cvt_f32_to_bf16<<<2048, 256, 0, stream>>>(x,      x_bf,  T_DIM * D_DIM / 4);
  cvt_f32_to_bf16<<<2048, 256, 0, stream>>>(W_attn, wa_bf, 3 * D_DIM * D_DIM / 4);
  cvt_f32_to_bf16<<<2048, 256, 0, stream>>>(W_proj, wp_bf, D_DIM * D_DIM / 4);

  gemm_bt_bias<<<dim3(3 * D_DIM / 128, T_DIM / 128), 256, 0, stream>>>(
      x_bf, wa_bf, b_attn, qkv, T_DIM, 3 * D_DIM, D_DIM);

  ln_rope_kernel<<<(H_DIM * T_DIM) / 4, 256, 0, stream>>>(qkv, q_ln_w, k_ln_w, q_bf, k_bf);
  v_transpose_kernel<<<dim3(T_DIM / 32, C_DIM / 32, H_DIM), dim3(32, 8), 0, stream>>>(qkv, vt);

  attn_kernel<<<dim3(T_DIM / 64, H_DIM), 256, 0, stream>>>(q_bf, k_bf, vt, ao);

  gemm_bt_bias<<<dim3(D_DIM / 128, T_DIM / 128), 256, 0, stream>>>(
      ao, wp_bf, b_proj, (float*)d_out, T_DIM, D_DIM, D_DIM);
}